// Round 4
// baseline (954.929 us; speedup 1.0000x reference)
//
#include <hip/hip_runtime.h>
#include <hip/hip_bf16.h>
#include <math.h>

// Problem constants (B=4, C=1024, d=1024)
#define T_TOK 4096
#define D     1024
#define DFF   4096
#define NEXP  8
#define CAP   1280   // floor(2*1.25*4096/8)=1280, already even
#define TOPK  2

typedef __bf16 bf16x8 __attribute__((ext_vector_type(8)));
typedef float floatx4 __attribute__((ext_vector_type(4)));

__device__ __forceinline__ unsigned short f2bf(float f) {
  union { float f; unsigned u; } un; un.f = f;
  unsigned r = un.u + 0x7FFF + ((un.u >> 16) & 1);  // RNE
  return (unsigned short)(r >> 16);
}

// ---------------------------------------------------------------------------
// Router (unchanged, verified): top-2, lowest-index tie-break, softmax.
// ---------------------------------------------------------------------------
__global__ __launch_bounds__(256) void router_kernel(
    const float* __restrict__ x, const float* __restrict__ wg,
    int* __restrict__ top_e, float* __restrict__ top_p) {
  int t = blockIdx.x * 4 + (threadIdx.x >> 6);
  int lane = threadIdx.x & 63;
  if (t >= T_TOK) return;
  const float* xr = x + (size_t)t * D;
  float acc[NEXP];
#pragma unroll
  for (int e = 0; e < NEXP; e++) acc[e] = 0.f;
  for (int dd = lane; dd < D; dd += 64) {
    float xv = xr[dd];
    const float* wr = wg + dd * NEXP;
#pragma unroll
    for (int e = 0; e < NEXP; e++) acc[e] += xv * wr[e];
  }
#pragma unroll
  for (int off = 32; off > 0; off >>= 1) {
#pragma unroll
    for (int e = 0; e < NEXP; e++) acc[e] += __shfl_xor(acc[e], off, 64);
  }
  if (lane == 0) {
    int b0 = 0; float v0 = acc[0];
    for (int e = 1; e < NEXP; e++) if (acc[e] > v0) { v0 = acc[e]; b0 = e; }
    int b1 = -1; float v1 = -INFINITY;
    for (int e = 0; e < NEXP; e++) if (e != b0 && acc[e] > v1) { v1 = acc[e]; b1 = e; }
    float e1 = expf(v1 - v0);
    float s = 1.0f + e1;
    top_e[t * 2 + 0] = b0; top_e[t * 2 + 1] = b1;
    top_p[t * 2 + 0] = 1.0f / s; top_p[t * 2 + 1] = e1 / s;
  }
}

// ---------------------------------------------------------------------------
// Rank/capacity (unchanged, verified): nanoMoE cumsum semantics via wave
// shuffles; also clears slot_token.
// ---------------------------------------------------------------------------
__global__ __launch_bounds__(1024) void rank_kernel(
    const int* __restrict__ top_e, const float* __restrict__ top_p,
    int* __restrict__ slot_token, int* __restrict__ tok_slot,
    float* __restrict__ tok_w) {
  __shared__ int wsum[16][NEXP];
  __shared__ int wscan[16][NEXP];
  int tid = threadIdx.x;
  int lane = tid & 63, w = tid >> 6;

  for (int s = tid; s < NEXP * CAP; s += 1024) slot_token[s] = -1;
  __syncthreads();

  int base[NEXP];
#pragma unroll
  for (int e = 0; e < NEXP; e++) base[e] = 0;

  for (int k = 0; k < TOPK; k++) {
    int cnt[NEXP];
#pragma unroll
    for (int e = 0; e < NEXP; e++) cnt[e] = 0;
    int eloc[4];
#pragma unroll
    for (int i = 0; i < 4; i++) {
      int t = tid * 4 + i;
      int e = top_e[t * 2 + k];
      eloc[i] = e;
#pragma unroll
      for (int q = 0; q < NEXP; q++) cnt[q] += (q == e);
    }
    int inc[NEXP];
#pragma unroll
    for (int e = 0; e < NEXP; e++) inc[e] = cnt[e];
    for (int off = 1; off < 64; off <<= 1) {
#pragma unroll
      for (int e = 0; e < NEXP; e++) {
        int v = __shfl_up(inc[e], off, 64);
        if (lane >= off) inc[e] += v;
      }
    }
    if (lane == 63)
#pragma unroll
      for (int e = 0; e < NEXP; e++) wsum[w][e] = inc[e];
    __syncthreads();
    if (w == 0 && lane < 16) {
      int s[NEXP];
#pragma unroll
      for (int e = 0; e < NEXP; e++) s[e] = wsum[lane][e];
      for (int off = 1; off < 16; off <<= 1) {
#pragma unroll
        for (int e = 0; e < NEXP; e++) {
          int v = __shfl_up(s[e], off, 64);
          if (lane >= off) s[e] += v;
        }
      }
#pragma unroll
      for (int e = 0; e < NEXP; e++) wscan[lane][e] = s[e];
    }
    __syncthreads();
    int excl[NEXP];
#pragma unroll
    for (int e = 0; e < NEXP; e++)
      excl[e] = inc[e] - cnt[e] + (w ? wscan[w - 1][e] : 0) + base[e];

    int run[NEXP];
#pragma unroll
    for (int e = 0; e < NEXP; e++) run[e] = 0;
#pragma unroll
    for (int i = 0; i < 4; i++) {
      int t = tid * 4 + i;
      int e = eloc[i];
      int r = 0;
#pragma unroll
      for (int q = 0; q < NEXP; q++)
        if (q == e) { r = excl[q] + run[q]; run[q]++; }
      if (r < CAP) {
        slot_token[e * CAP + r] = t;
        tok_slot[t * 2 + k] = e * CAP + r;
      } else {
        tok_slot[t * 2 + k] = -1;
      }
      tok_w[t * 2 + k] = top_p[t * 2 + k];
    }
#pragma unroll
    for (int e = 0; e < NEXP; e++) base[e] += wscan[15][e];
    __syncthreads();
  }
}

// ---------------------------------------------------------------------------
// Gather + fp32->bf16 (unchanged, verified).
// ---------------------------------------------------------------------------
__global__ __launch_bounds__(256) void gather_cvt_kernel(
    const float* __restrict__ x, const int* __restrict__ slot_token,
    unsigned short* __restrict__ xb) {
  int slot = blockIdx.x;
  int tok = slot_token[slot];
  int i = threadIdx.x;
  float4 v = make_float4(0.f, 0.f, 0.f, 0.f);
  if (tok >= 0) v = ((const float4*)(x + (size_t)tok * D))[i];
  ushort4 o;
  o.x = f2bf(v.x); o.y = f2bf(v.y); o.z = f2bf(v.z); o.w = f2bf(v.w);
  ((ushort4*)(xb + (size_t)slot * D))[i] = o;
}

// ---------------------------------------------------------------------------
// Transpose + fp32->bf16 (unchanged, verified).
// ---------------------------------------------------------------------------
__global__ __launch_bounds__(256) void transpose_cvt_kernel(
    const float* __restrict__ src, unsigned short* __restrict__ dst,
    int R, int Cc) {
  __shared__ float tile[64][65];
  int e = blockIdx.z;
  src += (size_t)e * R * Cc;
  dst += (size_t)e * R * Cc;
  int r0 = blockIdx.y * 64, c0 = blockIdx.x * 64;
  int tr = threadIdx.x >> 4;
  int tc = (threadIdx.x & 15) * 4;
#pragma unroll
  for (int i = 0; i < 64; i += 16) {
    float4 v = *(const float4*)(src + (size_t)(r0 + tr + i) * Cc + c0 + tc);
    tile[tr + i][tc + 0] = v.x;
    tile[tr + i][tc + 1] = v.y;
    tile[tr + i][tc + 2] = v.z;
    tile[tr + i][tc + 3] = v.w;
  }
  __syncthreads();
#pragma unroll
  for (int i = 0; i < 64; i += 16) {
    int c = tr + i, r = tc;
    ushort4 o;
    o.x = f2bf(tile[r + 0][c]);
    o.y = f2bf(tile[r + 1][c]);
    o.z = f2bf(tile[r + 2][c]);
    o.w = f2bf(tile[r + 3][c]);
    *(ushort4*)(dst + (size_t)(c0 + c) * R + r0 + r) = o;
  }
}

// ---------------------------------------------------------------------------
// Register-streaming bf16 MFMA GEMM: NO LDS, NO BARRIERS.
// Block 256 thr = 4 waves (2x2), block tile 128x128, wave tile 64x64 =
// 4x4 MFMA tiles of 16x16x32. Fragments loaded straight from global
// (L1/L2-cached), double-buffered in registers; each wave fully independent
// so the compiler emits fine-grained vmcnt(N) instead of a barrier drain.
// Fragment mapping identical to the verified R2/R3 LDS path.
// MODE 0: h = gelu(xb @ cfc_t^T) bf16 out; K=1024. Grid (e, mt, nt).
// MODE 1: eo_half = h @ cproj_t^T fp32 out, split-K x2; K-half=2048.
//         Grid (e, mt, kh*8+nt).
// ---------------------------------------------------------------------------
template <int MODE>
__global__ __launch_bounds__(256, 2) void gemm_stream_kernel(
    const unsigned short* __restrict__ A,
    const unsigned short* __restrict__ Bt,
    void* __restrict__ Cv) {
  constexpr int MM = CAP;
  constexpr int NN = (MODE == 0) ? DFF : D;
  constexpr int LDA = (MODE == 0) ? D : DFF;
  constexpr int KLEN = (MODE == 0) ? D : DFF / 2;

  int e = blockIdx.x, mt = blockIdx.y, nt, kh;
  if (MODE == 0) { nt = blockIdx.z; kh = 0; }
  else           { nt = blockIdx.z & 7; kh = blockIdx.z >> 3; }

  int tid = threadIdx.x;
  int wave = tid >> 6, lane = tid & 63;
  int fr = lane & 15, fq = lane >> 4;

  int wm = mt * 128 + (wave >> 1) * 64;  // absolute row of wave tile
  int wn = nt * 128 + (wave & 1) * 64;   // absolute col of wave tile

  // Lane base pointers (k-offset baked in; advance by elements along k).
  const unsigned short* Ab =
      A + (size_t)e * MM * LDA + (size_t)kh * KLEN + (size_t)(wm + fr) * LDA + fq * 8;
  const unsigned short* Bb =
      Bt + (size_t)e * NN * LDA + (size_t)kh * KLEN + (size_t)(wn + fr) * LDA + fq * 8;

  floatx4 acc[4][4];
#pragma unroll
  for (int i = 0; i < 4; i++)
#pragma unroll
    for (int j = 0; j < 4; j++) acc[i][j] = (floatx4){0.f, 0.f, 0.f, 0.f};

  bf16x8 a0[4], b0[4], a1[4], b1[4];

#define LOADF(abuf, bbuf, koff)                                             \
  {                                                                         \
    _Pragma("unroll") for (int mi = 0; mi < 4; mi++)                        \
        abuf[mi] = *(const bf16x8*)(Ab + (size_t)mi * 16 * LDA + (koff));   \
    _Pragma("unroll") for (int ni = 0; ni < 4; ni++)                        \
        bbuf[ni] = *(const bf16x8*)(Bb + (size_t)ni * 16 * LDA + (koff));   \
  }

#define MFMA16(abuf, bbuf)                                                  \
  {                                                                         \
    _Pragma("unroll") for (int mi = 0; mi < 4; mi++)                        \
        _Pragma("unroll") for (int ni = 0; ni < 4; ni++)                    \
            acc[mi][ni] = __builtin_amdgcn_mfma_f32_16x16x32_bf16(          \
                abuf[mi], bbuf[ni], acc[mi][ni], 0, 0, 0);                  \
  }

  LOADF(a0, b0, 0);
  LOADF(a1, b1, 32);
  for (int k0 = 0; k0 < KLEN - 64; k0 += 64) {
    MFMA16(a0, b0);
    LOADF(a0, b0, k0 + 64);
    MFMA16(a1, b1);
    LOADF(a1, b1, k0 + 96);
  }
  MFMA16(a0, b0);
  MFMA16(a1, b1);
#undef LOADF
#undef MFMA16

  // Epilogue. C/D layout (verified): col = lane&15, row = (lane>>4)*4 + reg.
  if (MODE == 0) {
    unsigned short* Cb = (unsigned short*)Cv + (size_t)e * MM * NN;
#pragma unroll
    for (int mi = 0; mi < 4; mi++)
#pragma unroll
      for (int ni = 0; ni < 4; ni++)
#pragma unroll
        for (int r = 0; r < 4; r++) {
          float v = acc[mi][ni][r];
          v = 0.5f * v * (1.f + erff(v * 0.70710678118654752f));
          Cb[(size_t)(wm + mi * 16 + fq * 4 + r) * NN + (wn + ni * 16 + fr)] =
              f2bf(v);
        }
  } else {
    float* Cf = (float*)Cv + ((size_t)kh * NEXP + e) * MM * NN;
#pragma unroll
    for (int mi = 0; mi < 4; mi++)
#pragma unroll
      for (int ni = 0; ni < 4; ni++)
#pragma unroll
        for (int r = 0; r < 4; r++)
          Cf[(size_t)(wm + mi * 16 + fq * 4 + r) * NN + (wn + ni * 16 + fr)] =
              acc[mi][ni][r];
  }
}

// ---------------------------------------------------------------------------
// Combine (unchanged, verified): out[t,:] = sum_k kept(w_k * (eo0+eo1)).
// ---------------------------------------------------------------------------
__global__ __launch_bounds__(256) void combine_kernel(
    const float* __restrict__ eo, const int* __restrict__ tok_slot,
    const float* __restrict__ tok_w, float* __restrict__ out) {
  int t = blockIdx.x;
  int i = threadIdx.x;
  const size_t half = (size_t)NEXP * CAP * D;
  float4 acc = make_float4(0.f, 0.f, 0.f, 0.f);
#pragma unroll
  for (int k = 0; k < TOPK; k++) {
    int s = tok_slot[t * 2 + k];
    if (s >= 0) {
      float w = tok_w[t * 2 + k];
      float4 v0 = ((const float4*)(eo + (size_t)s * D))[i];
      float4 v1 = ((const float4*)(eo + half + (size_t)s * D))[i];
      acc.x += w * (v0.x + v1.x);
      acc.y += w * (v0.y + v1.y);
      acc.z += w * (v0.z + v1.z);
      acc.w += w * (v0.w + v1.w);
    }
  }
  ((float4*)(out + (size_t)t * D))[i] = acc;
}

// ---------------------------------------------------------------------------
extern "C" void kernel_launch(void* const* d_in, const int* in_sizes, int n_in,
                              void* d_out, int out_size, void* d_ws, size_t ws_size,
                              hipStream_t stream) {
  const float* x     = (const float*)d_in[0];  // [4,1024,1024]
  const float* wg    = (const float*)d_in[1];  // [1024,8]
  const float* cfc   = (const float*)d_in[2];  // [8,1024,4096]
  const float* cproj = (const float*)d_in[3];  // [8,4096,1024]
  float* out = (float*)d_out;

  char* ws = (char*)d_ws;
  size_t off = 0;
  auto alloc = [&](size_t bytes) -> void* {
    void* p = ws + off;
    off += (bytes + 255) & ~(size_t)255;
    return p;
  };
  int*   top_e      = (int*)  alloc((size_t)T_TOK * 2 * 4);
  float* top_p      = (float*)alloc((size_t)T_TOK * 2 * 4);
  int*   slot_token = (int*)  alloc((size_t)NEXP * CAP * 4);
  int*   tok_slot   = (int*)  alloc((size_t)T_TOK * 2 * 4);
  float* tok_w      = (float*)alloc((size_t)T_TOK * 2 * 4);
  unsigned short* xb      = (unsigned short*)alloc((size_t)NEXP * CAP * D * 2);   // 20 MB
  unsigned short* cfc_t   = (unsigned short*)alloc((size_t)NEXP * D * DFF * 2);   // 67 MB [e][DFF][D]
  unsigned short* cproj_t = (unsigned short*)alloc((size_t)NEXP * DFF * D * 2);   // 67 MB [e][D][DFF]
  unsigned short* h       = (unsigned short*)alloc((size_t)NEXP * CAP * DFF * 2); // 84 MB
  // eo split-K halves: [2][NEXP][CAP][D] fp32 = 84 MB, aliases dead xb+cfc_t (87.9 MB).
  float* eo = (float*)xb;

  // Weight convert+transpose (independent of routing).
  transpose_cvt_kernel<<<dim3(DFF / 64, D / 64, NEXP), 256, 0, stream>>>(
      cfc, cfc_t, D, DFF);
  transpose_cvt_kernel<<<dim3(D / 64, DFF / 64, NEXP), 256, 0, stream>>>(
      cproj, cproj_t, DFF, D);

  router_kernel<<<T_TOK / 4, 256, 0, stream>>>(x, wg, top_e, top_p);
  rank_kernel<<<1, 1024, 0, stream>>>(top_e, top_p, slot_token, tok_slot, tok_w);
  gather_cvt_kernel<<<NEXP * CAP, 256, 0, stream>>>(x, slot_token, xb);

  // GEMM1: h = gelu(xb @ cfc_t^T). Grid (e, mt, nt): XCD = e.
  gemm_stream_kernel<0><<<dim3(NEXP, CAP / 128, DFF / 128), 256, 0, stream>>>(
      xb, cfc_t, h);
  // GEMM2: eo{0,1} = h @ cproj_t^T split-K. Grid (e, mt, kh*8+nt): XCD = e.
  gemm_stream_kernel<1><<<dim3(NEXP, CAP / 128, 2 * D / 128), 256, 0, stream>>>(
      h, cproj_t, eo);

  combine_kernel<<<T_TOK, 256, 0, stream>>>(eo, tok_slot, tok_w, out);
}